// Round 3
// baseline (512.638 us; speedup 1.0000x reference)
//
#include <hip/hip_runtime.h>
#include <hip/hip_bf16.h>
#include <math.h>

// ---------------------------------------------------------------------------
// HyperParamNet — round 3.
// Round-2 counters: kA 337us, VALUBusy 36.6%, VGPR 52 (acc[64] stuck in
// AGPRs), MfmaUtil 0. conv2 (7168 of 9184 FMA/pixel) is a 112x64 GEMM ->
// move it to MFMA:
//   kA1: conv1 (grouped 3x3) VALU fp32 -> t1 bf16 [pix][112]  (per 4-batch
//        chunk, 58.7MB, aliased over the b1/b2 region; 2 chunks keep ws at
//        the proven 71.3MB)
//   kA2: C[64][pix] = W[64][112] x t1 via mfma_f32_16x16x32_bf16,
//        epilogue computes xc (tb per-pixel max/mean) and ta spatial
//        sum/max (running per-lane accs -> block reduce -> 1 atomic/ch).
// kB / kC1-3 unchanged from round 2.
// ---------------------------------------------------------------------------

using s16x8 = __attribute__((ext_vector_type(8))) short;
using f32x4 = __attribute__((ext_vector_type(4))) float;

__device__ __forceinline__ float leaky(float x) {
    return x >= 0.f ? x : 0.01f * x;
}

// float -> bf16 bits, round-to-nearest-even
__device__ __forceinline__ unsigned short f2bf(float f) {
    unsigned x = __float_as_uint(f);
    return (unsigned short)((x + 0x7FFFu + ((x >> 16) & 1u)) >> 16);
}

// ---------------------------------------------------------------------------
__global__ void kInit(float* __restrict__ sums, unsigned* __restrict__ maxu) {
    int t = threadIdx.x;   // 256 == 8*32
    sums[t] = 0.f;
    maxu[t] = 0u;
}

// ---------------------------------------------------------------------------
// kA1: grouped conv3x3 + relu -> t1 bf16, layout [bl][pixel][112ch].
// Grid (16,16,4) tiles of 16x16 pixels, block 256 (1 thread/pixel).
// ---------------------------------------------------------------------------
__global__ __launch_bounds__(256) void kA1(
    const float* __restrict__ y, const float* __restrict__ mask,
    const float* __restrict__ fw1, const float* __restrict__ fb1,
    short* __restrict__ t1, int chunk)
{
    __shared__ float2 sh[14 * 324];   // 14 groups x 18x18 halo x (y,mask)

    const int bl = blockIdx.z;        // batch within chunk
    const int b  = chunk * 4 + bl;    // global batch
    const int h0 = blockIdx.y << 4;
    const int w0 = blockIdx.x << 4;
    const int tid = threadIdx.x;
    const int ty = tid >> 4, tx = tid & 15;

    const int h = h0 + ty, w = w0 + tx;
    short* trow = t1 + ((((size_t)bl << 16) + (h << 8) + w) * 112);

    #pragma unroll 1
    for (int half = 0; half < 2; ++half) {
        if (half) __syncthreads();
        const int TOT = 14 * 324;
        for (int i = tid; i < TOT; i += 256) {
            int gl  = i / 324;
            int rem = i - gl * 324;
            int r   = rem / 18;
            int c   = rem - r * 18;
            int oc  = half * 14 + gl;
            int gh = h0 + r - 1, gw = w0 + c - 1;
            float2 v = make_float2(0.f, 0.f);
            if ((unsigned)gh < 256u && (unsigned)gw < 256u) {
                size_t off = (((size_t)b * 28 + oc) << 16) + (gh << 8) + gw;
                v.x = y[off];
                v.y = mask[off];
            }
            sh[i] = v;
        }
        __syncthreads();

        #pragma unroll 1
        for (int gl = 0; gl < 14; ++gl) {
            const int g = half * 14 + gl;
            float r0 = fb1[4*g], r1 = fb1[4*g+1], r2 = fb1[4*g+2], r3 = fb1[4*g+3];
            const float* w1 = fw1 + (size_t)g * 72;
            const float2* shp = sh + gl * 324 + ty * 18 + tx;
            #pragma unroll
            for (int dy = 0; dy < 3; ++dy) {
                #pragma unroll
                for (int dx = 0; dx < 3; ++dx) {
                    float2 v = shp[dy*18 + dx];
                    int k = dy*3 + dx;
                    r0 += w1[     k]*v.x + w1[ 9 + k]*v.y;
                    r1 += w1[18 + k]*v.x + w1[27 + k]*v.y;
                    r2 += w1[36 + k]*v.x + w1[45 + k]*v.y;
                    r3 += w1[54 + k]*v.x + w1[63 + k]*v.y;
                }
            }
            short4 q;
            q.x = (short)f2bf(fmaxf(r0, 0.f));
            q.y = (short)f2bf(fmaxf(r1, 0.f));
            q.z = (short)f2bf(fmaxf(r2, 0.f));
            q.w = (short)f2bf(fmaxf(r3, 0.f));
            *(short4*)(trow + 4*g) = q;
        }
    }
}

// ---------------------------------------------------------------------------
// kA2: conv2 as MFMA GEMM + fused reductions.
// C[64 out][65536 pix] per batch; wave = 4 row-tiles x 16-pixel col-tile.
// A (weights) from LDS (K padded to 136, zeros for k>=112); B (t1) from
// global, each 16B lane-load feeds 4 MFMAs.
// Grid (256, 4): 256 pixel-blocks x 4 batches-in-chunk; block 256 = 4 waves,
// wave covers 64 pixels (4 pixel-groups).
// ---------------------------------------------------------------------------
__global__ __launch_bounds__(256, 2) void kA2(
    const short* __restrict__ t1, const float* __restrict__ fw2,
    const float* __restrict__ fb2, float* __restrict__ xc,
    float* __restrict__ sums, unsigned* __restrict__ maxu, int chunk)
{
    __shared__ short Wl[64 * 136];      // 17408 B, bf16 weights, K-padded
    __shared__ float red[4 * 32 * 2];   // per-wave ta partials

    const int bl = blockIdx.y;
    const int b  = chunk * 4 + bl;
    const int tid = threadIdx.x;
    const int wv = tid >> 6, ln = tid & 63;
    const int col = ln & 15, lg = ln >> 4;

    // stage W as bf16, zero-pad K 112..135
    for (int i = tid; i < 64 * 136; i += 256) {
        int o = i / 136, k = i - o * 136;
        Wl[i] = (k < 112) ? (short)f2bf(fw2[o * 112 + k]) : (short)0;
    }
    __syncthreads();

    // A fragments: lane holds W[row=tile*16+col][k = s*32 + lg*8 .. +8)
    s16x8 A[4][4];
    #pragma unroll
    for (int t = 0; t < 4; ++t)
        #pragma unroll
        for (int s = 0; s < 4; ++s)
            A[t][s] = *(const s16x8*)&Wl[(t*16 + col)*136 + s*32 + lg*8];

    float bias[4][4];
    #pragma unroll
    for (int t = 0; t < 4; ++t)
        #pragma unroll
        for (int r = 0; r < 4; ++r)
            bias[t][r] = fb2[t*16 + lg*4 + r];

    float run_s[2][4], run_m[2][4];
    #pragma unroll
    for (int t = 0; t < 2; ++t)
        #pragma unroll
        for (int r = 0; r < 4; ++r) { run_s[t][r] = 0.f; run_m[t][r] = -3.4e38f; }

    const short* tb = t1 + (size_t)bl * 65536 * 112;
    const int pbase = blockIdx.x * 256 + wv * 64;
    float* xc0 = xc + (((size_t)b * 2) << 16);
    float* xc1 = xc0 + 65536;

    #pragma unroll 1
    for (int pg = 0; pg < 4; ++pg) {
        const int p0 = pbase + pg * 16;
        // B fragments: lane holds t1[pix=p0+col][k = s*32 + lg*8 .. +8)
        const short* rowp = tb + (size_t)(p0 + col) * 112 + lg * 8;
        s16x8 B[4];
        #pragma unroll
        for (int s = 0; s < 4; ++s) B[s] = *(const s16x8*)(rowp + s * 32);

        f32x4 acc[4];
        #pragma unroll
        for (int t = 0; t < 4; ++t) {
            f32x4 c; c[0] = bias[t][0]; c[1] = bias[t][1];
            c[2] = bias[t][2]; c[3] = bias[t][3];
            #pragma unroll
            for (int s = 0; s < 4; ++s)
                c = __builtin_amdgcn_mfma_f32_16x16x32_bf16(A[t][s], B[s], c, 0, 0, 0);
            acc[t] = c;
        }

        // tb (out-ch 32..63 = tiles 2,3): per-pixel max & mean -> xc
        float m8 = -3.4e38f, s8 = 0.f;
        #pragma unroll
        for (int t = 2; t < 4; ++t)
            #pragma unroll
            for (int r = 0; r < 4; ++r) {
                float v = acc[t][r];
                m8 = fmaxf(m8, v); s8 += v;
            }
        m8 = fmaxf(m8, __shfl_xor(m8, 16));
        m8 = fmaxf(m8, __shfl_xor(m8, 32));
        s8 += __shfl_xor(s8, 16);
        s8 += __shfl_xor(s8, 32);
        if (ln < 16) {
            xc0[p0 + ln] = m8;
            xc1[p0 + ln] = s8 * (1.f / 32.f);
        }

        // ta (out-ch 0..31 = tiles 0,1): defer, accumulate per-lane
        #pragma unroll
        for (int t = 0; t < 2; ++t)
            #pragma unroll
            for (int r = 0; r < 4; ++r) {
                float v = acc[t][r];
                run_s[t][r] += v;
                run_m[t][r] = fmaxf(run_m[t][r], v);
            }
    }

    // wave reduce ta over the 16 pixel columns
    #pragma unroll
    for (int t = 0; t < 2; ++t)
        #pragma unroll
        for (int r = 0; r < 4; ++r) {
            float s = run_s[t][r], m = run_m[t][r];
            #pragma unroll
            for (int off = 1; off < 16; off <<= 1) {
                s += __shfl_xor(s, off);
                m = fmaxf(m, __shfl_xor(m, off));
            }
            if (col == 0) {
                int ch = t*16 + lg*4 + r;
                red[(wv*32 + ch)*2 + 0] = s;
                red[(wv*32 + ch)*2 + 1] = m;
            }
        }
    __syncthreads();
    if (tid < 32) {
        float s = red[tid*2] + red[(32+tid)*2] + red[(64+tid)*2] + red[(96+tid)*2];
        float m = fmaxf(fmaxf(red[tid*2+1], red[(32+tid)*2+1]),
                        fmaxf(red[(64+tid)*2+1], red[(96+tid)*2+1]));
        atomicAdd(&sums[b*32 + tid], s);
        unsigned ub  = __float_as_uint(m);
        unsigned key = (ub & 0x80000000u) ? ~ub : (ub | 0x80000000u);
        atomicMax(&maxu[b*32 + tid], key);
    }
}

// ---------------------------------------------------------------------------
// Kernel B: finish ta mean/max, run pgm MLP on both, alpha = sum.
// ---------------------------------------------------------------------------
__global__ __launch_bounds__(256) void kB(
    const float* __restrict__ sums, const unsigned* __restrict__ maxu,
    const float* __restrict__ aw1, const float* __restrict__ ab1,
    const float* __restrict__ aw2, const float* __restrict__ ab2,
    const float* __restrict__ aw3, const float* __restrict__ ab3,
    float* __restrict__ out)
{
    __shared__ float xa[8][32], xm[8][32], h1a[8][32], h1m[8][32];
    const int tid = threadIdx.x;
    const int b = tid >> 5, i = tid & 31;

    xa[b][i] = sums[b*32 + i] * (1.f/65536.f);
    unsigned u = maxu[b*32 + i];
    unsigned bits = (u & 0x80000000u) ? (u ^ 0x80000000u) : ~u;
    xm[b][i] = __uint_as_float(bits);
    __syncthreads();

    float sa = ab1[i], sm = ab1[i];
    #pragma unroll
    for (int j = 0; j < 32; ++j) {
        float w = aw1[i*32 + j];
        sa += w * xa[b][j]; sm += w * xm[b][j];
    }
    __syncthreads();
    h1a[b][i] = leaky(sa); h1m[b][i] = leaky(sm);
    __syncthreads();

    sa = ab2[i]; sm = ab2[i];
    #pragma unroll
    for (int j = 0; j < 32; ++j) {
        float w = aw2[i*32 + j];
        sa += w * h1a[b][j]; sm += w * h1m[b][j];
    }
    float h2a = leaky(sa), h2m = leaky(sm);

    float pa = aw3[i] * h2a, pm = aw3[i] * h2m;
    #pragma unroll
    for (int off = 16; off > 0; off >>= 1) {
        pa += __shfl_xor(pa, off);
        pm += __shfl_xor(pm, off);
    }
    if (i == 0) {
        float za = fmaxf(pa + ab3[0], 0.f) + 1e-6f;
        float zm = fmaxf(pm + ab3[0], 0.f) + 1e-6f;
        out[b] = za + zm;
    }
}

// ---------------------------------------------------------------------------
// Kernel C1: b1 = leaky(conv3x3(xc, bw1, bb1)), 2 -> 16 channels.
// ---------------------------------------------------------------------------
__global__ __launch_bounds__(256) void kC1(
    const float* __restrict__ xc, const float* __restrict__ bw1,
    const float* __restrict__ bb1, float* __restrict__ b1out)
{
    const int idx = blockIdx.x * 256 + threadIdx.x;
    const int b = idx >> 16, rem = idx & 65535;
    const int h = rem >> 8, w = rem & 255;
    float acc[16];
    #pragma unroll
    for (int o = 0; o < 16; ++o) acc[o] = bb1[o];
    #pragma unroll
    for (int ic = 0; ic < 2; ++ic) {
        const float* src = xc + (((size_t)b*2 + ic) << 16);
        #pragma unroll
        for (int dy = 0; dy < 3; ++dy) {
            int hh = h + dy - 1;
            #pragma unroll
            for (int dx = 0; dx < 3; ++dx) {
                int ww = w + dx - 1;
                float v = ((unsigned)hh < 256u && (unsigned)ww < 256u)
                          ? src[(hh << 8) + ww] : 0.f;
                int k = dy*3 + dx;
                #pragma unroll
                for (int o = 0; o < 16; ++o)
                    acc[o] += bw1[(o*2 + ic)*9 + k] * v;
            }
        }
    }
    #pragma unroll
    for (int o = 0; o < 16; ++o)
        b1out[(((size_t)b*16 + o) << 16) + rem] = leaky(acc[o]);
}

// ---------------------------------------------------------------------------
// Kernel C2: b2 = leaky(conv3x3(b1, bw2, bb2)), 16 -> 16 channels.
// ---------------------------------------------------------------------------
__global__ __launch_bounds__(256) void kC2(
    const float* __restrict__ b1in, const float* __restrict__ bw2,
    const float* __restrict__ bb2, float* __restrict__ b2out)
{
    const int idx = blockIdx.x * 256 + threadIdx.x;
    const int b = idx >> 16, rem = idx & 65535;
    const int h = rem >> 8, w = rem & 255;
    float acc[16];
    #pragma unroll
    for (int o = 0; o < 16; ++o) acc[o] = bb2[o];
    #pragma unroll 1
    for (int ic = 0; ic < 16; ++ic) {
        const float* src = b1in + (((size_t)b*16 + ic) << 16);
        #pragma unroll
        for (int dy = 0; dy < 3; ++dy) {
            int hh = h + dy - 1;
            #pragma unroll
            for (int dx = 0; dx < 3; ++dx) {
                int ww = w + dx - 1;
                float v = ((unsigned)hh < 256u && (unsigned)ww < 256u)
                          ? src[(hh << 8) + ww] : 0.f;
                int k = dy*3 + dx;
                #pragma unroll
                for (int o = 0; o < 16; ++o)
                    acc[o] += bw2[(o*16 + ic)*9 + k] * v;
            }
        }
    }
    #pragma unroll
    for (int o = 0; o < 16; ++o)
        b2out[(((size_t)b*16 + o) << 16) + rem] = leaky(acc[o]);
}

// ---------------------------------------------------------------------------
// Kernel C3: beta = sigmoid(conv3x3(b2, bw3, bb3)), 16 -> 1 channel.
// ---------------------------------------------------------------------------
__global__ __launch_bounds__(256) void kC3(
    const float* __restrict__ b2in, const float* __restrict__ bw3,
    const float* __restrict__ bb3, float* __restrict__ betaout)
{
    const int idx = blockIdx.x * 256 + threadIdx.x;
    const int b = idx >> 16, rem = idx & 65535;
    const int h = rem >> 8, w = rem & 255;
    float acc = bb3[0];
    #pragma unroll 1
    for (int ic = 0; ic < 16; ++ic) {
        const float* src = b2in + (((size_t)b*16 + ic) << 16);
        #pragma unroll
        for (int dy = 0; dy < 3; ++dy) {
            int hh = h + dy - 1;
            #pragma unroll
            for (int dx = 0; dx < 3; ++dx) {
                int ww = w + dx - 1;
                float v = ((unsigned)hh < 256u && (unsigned)ww < 256u)
                          ? src[(hh << 8) + ww] : 0.f;
                acc += bw3[ic*9 + dy*3 + dx] * v;
            }
        }
    }
    betaout[idx] = 1.f / (1.f + expf(-acc));
}

// ---------------------------------------------------------------------------
extern "C" void kernel_launch(void* const* d_in, const int* in_sizes, int n_in,
                              void* d_out, int out_size, void* d_ws, size_t ws_size,
                              hipStream_t stream) {
    const float* y    = (const float*)d_in[0];
    const float* mask = (const float*)d_in[1];
    const float* fw1  = (const float*)d_in[2];
    const float* fb1  = (const float*)d_in[3];
    const float* fw2  = (const float*)d_in[4];
    const float* fb2  = (const float*)d_in[5];
    const float* aw1  = (const float*)d_in[6];
    const float* ab1  = (const float*)d_in[7];
    const float* aw2  = (const float*)d_in[8];
    const float* ab2  = (const float*)d_in[9];
    const float* aw3  = (const float*)d_in[10];
    const float* ab3  = (const float*)d_in[11];
    const float* bw1  = (const float*)d_in[12];
    const float* bb1  = (const float*)d_in[13];
    const float* bw2  = (const float*)d_in[14];
    const float* bb2  = (const float*)d_in[15];
    const float* bw3  = (const float*)d_in[16];
    const float* bb3  = (const float*)d_in[17];
    float* out = (float*)d_out;

    char* ws = (char*)d_ws;
    float*    sums = (float*)ws;                       // 1 KB
    unsigned* maxu = (unsigned*)(ws + 1024);           // 1 KB
    float*    xc   = (float*)(ws + 4096);              // 4 MB
    // t1 (58.72 MB, bf16, per 4-batch chunk) aliases the b1/b2 region:
    // t1 fully consumed by kA2 before kC1 writes b1.
    short*    t1   = (short*)(ws + 4096 + 4194304);
    float*    b1   = (float*)(ws + 4096 + 4194304);
    float*    b2   = (float*)(ws + 4096 + 4194304 + 33554432);

    kInit<<<1, 256, 0, stream>>>(sums, maxu);
    for (int chunk = 0; chunk < 2; ++chunk) {
        kA1<<<dim3(16, 16, 4), 256, 0, stream>>>(y, mask, fw1, fb1, t1, chunk);
        kA2<<<dim3(256, 4), 256, 0, stream>>>(t1, fw2, fb2, xc, sums, maxu, chunk);
    }
    kB<<<1, 256, 0, stream>>>(sums, maxu, aw1, ab1, aw2, ab2, aw3, ab3, out);
    kC1<<<2048, 256, 0, stream>>>(xc, bw1, bb1, b1);
    kC2<<<2048, 256, 0, stream>>>(b1, bw2, bb2, b2);
    kC3<<<2048, 256, 0, stream>>>(b2, bw3, bb3, out + 8);
}

// Round 4
// 306.457 us; speedup vs baseline: 1.6728x; 1.6728x over previous
//
#include <hip/hip_runtime.h>
#include <hip/hip_bf16.h>
#include <math.h>

// ---------------------------------------------------------------------------
// HyperParamNet — round 4.
// Round-3 lesson: materializing t1 in HBM (117MB round trip, uncoalesced
// [pix][ch] writes) cost 460us across kA1/kA2. This round fuses everything:
//   kA: per K-chunk s (32 ch = 8 groups): stage (y,mask) halo in LDS ->
//       each lane computes conv1+relu for ITS OWN MFMA B-fragment channels
//       (pixel=col, ch=32s+8lg..+8) -> bf16 -> 16 MFMAs accumulate
//       C[64 out][16 pix] per (wave,pg). Epilogue (xc + ta reduce) is
//       round-3's proven code. No t1 anywhere.
// Fragment layouts verified correct by round-3 absmax.
// kB / kC1-3 unchanged.
// ---------------------------------------------------------------------------

using s16x8 = __attribute__((ext_vector_type(8))) short;
using f32x4 = __attribute__((ext_vector_type(4))) float;

__device__ __forceinline__ float leaky(float x) {
    return x >= 0.f ? x : 0.01f * x;
}

// float -> bf16 bits, round-to-nearest-even
__device__ __forceinline__ unsigned short f2bf(float f) {
    unsigned x = __float_as_uint(f);
    return (unsigned short)((x + 0x7FFFu + ((x >> 16) & 1u)) >> 16);
}

// ---------------------------------------------------------------------------
__global__ void kInit(float* __restrict__ sums, unsigned* __restrict__ maxu) {
    int t = threadIdx.x;   // 256 == 8*32
    sums[t] = 0.f;
    maxu[t] = 0u;
}

// ---------------------------------------------------------------------------
// kA: fused conv1(grouped 3x3, VALU) + conv2(1x1, MFMA) + xc + ta reduce.
// Grid (16,16,8): 16x16 pixel tiles. Block 256 = 4 waves; wave wv owns tile
// rows 4wv..4wv+3 (pg=row-in-quad), lane (col,lg): pixel x=col, k-slice lg.
// ---------------------------------------------------------------------------
__global__ __launch_bounds__(256, 2) void kA(
    const float* __restrict__ y, const float* __restrict__ mask,
    const float* __restrict__ fw1, const float* __restrict__ fb1,
    const float* __restrict__ fw2, const float* __restrict__ fb2,
    float* __restrict__ xc, float* __restrict__ sums, unsigned* __restrict__ maxu)
{
    __shared__ float2 shH[8 * 324];    // 8 groups x 18x18 halo (y,mask)  20736B
    __shared__ short  Wl[64 * 136];    // conv2 weights bf16, K-pad stride 17408B
    __shared__ float2 w1f2[112 * 9];   // conv1 weights (wy,wm) per ch      8064B
    __shared__ float  fbl[112];        // conv1 bias                         448B
    __shared__ float  red[4 * 32 * 2]; // ta partials                       1024B

    const int b  = blockIdx.z;
    const int h0 = blockIdx.y << 4;
    const int w0 = blockIdx.x << 4;
    const int tid = threadIdx.x;
    const int wv = tid >> 6, ln = tid & 63;
    const int col = ln & 15, lg = ln >> 4;

    // ---- one-time weight staging ----
    for (int i = tid; i < 112 * 9; i += 256) {
        int ch = i / 9, q = i - ch * 9;
        w1f2[i] = make_float2(fw1[ch * 18 + q], fw1[ch * 18 + 9 + q]);
    }
    if (tid < 112) fbl[tid] = fb1[tid];
    for (int i = tid; i < 64 * 136; i += 256) {
        int o = i / 136, k = i - o * 136;
        Wl[i] = (k < 112) ? (short)f2bf(fw2[o * 112 + k]) : (short)0;
    }

    // ---- C accumulators, init with conv2 bias ----
    f32x4 acc[4][4];   // [pg][t]
    #pragma unroll
    for (int t = 0; t < 4; ++t) {
        #pragma unroll
        for (int r = 0; r < 4; ++r) {
            float bv = fb2[t * 16 + lg * 4 + r];
            #pragma unroll
            for (int pg = 0; pg < 4; ++pg) acc[pg][t][r] = bv;
        }
    }

    // ---- K-chunk loop: 8 groups (32 temp-channels) per chunk ----
    #pragma unroll 1
    for (int s = 0; s < 4; ++s) {
        __syncthreads();   // previous chunk done reading shH
        const int ng = (s == 3) ? 4 : 8;   // chunk 3: groups 24..27 only
        for (int i = tid; i < ng * 324; i += 256) {
            int g = i / 324, rem = i - g * 324;
            int r = rem / 18, c = rem - r * 18;
            int gh = h0 + r - 1, gw = w0 + c - 1;
            float2 v = make_float2(0.f, 0.f);
            if ((unsigned)gh < 256u && (unsigned)gw < 256u) {
                size_t off = (((size_t)b * 28 + s * 8 + g) << 16) + (gh << 8) + gw;
                v.x = y[off];
                v.y = mask[off];
            }
            shH[i] = v;
        }
        __syncthreads();

        // A-fragments for this K-chunk (layout proven in round 3)
        s16x8 A[4];
        #pragma unroll
        for (int t = 0; t < 4; ++t)
            A[t] = *(const s16x8*)&Wl[(t * 16 + col) * 136 + s * 32 + lg * 8];

        // B-fragments: conv1 computed directly into this lane's slice
        s16x8 Bf[4];   // [pg]
        #pragma unroll
        for (int pg = 0; pg < 4; ++pg)
            #pragma unroll
            for (int j = 0; j < 8; ++j) Bf[pg][j] = 0;

        if (s < 3 || lg < 2) {     // s=3, lg>=2 -> channels >=112: stay zero
            #pragma unroll
            for (int gidx = 0; gidx < 2; ++gidx) {
                const int gl = 2 * lg + gidx;      // local group 0..7
                // 6 rows x 3 cols halo window covers all 4 pixel rows
                float2 hl[6][3];
                const float2* hb = &shH[gl * 324 + (4 * wv) * 18 + col];
                #pragma unroll
                for (int rr = 0; rr < 6; ++rr)
                    #pragma unroll
                    for (int cc = 0; cc < 3; ++cc)
                        hl[rr][cc] = hb[rr * 18 + cc];
                #pragma unroll
                for (int jj = 0; jj < 4; ++jj) {
                    const int chO = s * 32 + lg * 8 + gidx * 4 + jj;
                    float2 wq[9];                  // broadcast reads (~free)
                    #pragma unroll
                    for (int q = 0; q < 9; ++q) wq[q] = w1f2[chO * 9 + q];
                    const float base = fbl[chO];
                    #pragma unroll
                    for (int pg = 0; pg < 4; ++pg) {
                        float a = base;
                        #pragma unroll
                        for (int dy = 0; dy < 3; ++dy)
                            #pragma unroll
                            for (int dx = 0; dx < 3; ++dx) {
                                float2 h = hl[pg + dy][dx];
                                float2 w = wq[dy * 3 + dx];
                                a += w.x * h.x + w.y * h.y;
                            }
                        a = fmaxf(a, 0.f);
                        Bf[pg][gidx * 4 + jj] = (short)f2bf(a);
                    }
                }
            }
        }

        #pragma unroll
        for (int pg = 0; pg < 4; ++pg)
            #pragma unroll
            for (int t = 0; t < 4; ++t)
                acc[pg][t] = __builtin_amdgcn_mfma_f32_16x16x32_bf16(
                                 A[t], Bf[pg], acc[pg][t], 0, 0, 0);
    }

    // ---- epilogue (round-3 proven) ----
    float* xc0 = xc + (((size_t)b * 2) << 16);
    float* xc1 = xc0 + 65536;

    float run_s[2][4], run_m[2][4];
    #pragma unroll
    for (int t = 0; t < 2; ++t)
        #pragma unroll
        for (int r = 0; r < 4; ++r) { run_s[t][r] = 0.f; run_m[t][r] = -3.4e38f; }

    #pragma unroll
    for (int pg = 0; pg < 4; ++pg) {
        // tb (out-ch 32..63 = tiles 2,3): per-pixel max & mean -> xc
        float m8 = -3.4e38f, s8 = 0.f;
        #pragma unroll
        for (int t = 2; t < 4; ++t)
            #pragma unroll
            for (int r = 0; r < 4; ++r) {
                float v = acc[pg][t][r];
                m8 = fmaxf(m8, v); s8 += v;
            }
        m8 = fmaxf(m8, __shfl_xor(m8, 16));
        m8 = fmaxf(m8, __shfl_xor(m8, 32));
        s8 += __shfl_xor(s8, 16);
        s8 += __shfl_xor(s8, 32);
        if (ln < 16) {
            int row = h0 + 4 * wv + pg;
            xc0[(row << 8) + w0 + ln] = m8;
            xc1[(row << 8) + w0 + ln] = s8 * (1.f / 32.f);
        }
        // ta (out-ch 0..31 = tiles 0,1): running per-lane accumulate
        #pragma unroll
        for (int t = 0; t < 2; ++t)
            #pragma unroll
            for (int r = 0; r < 4; ++r) {
                float v = acc[pg][t][r];
                run_s[t][r] += v;
                run_m[t][r] = fmaxf(run_m[t][r], v);
            }
    }

    // wave reduce ta over the 16 pixel columns
    #pragma unroll
    for (int t = 0; t < 2; ++t)
        #pragma unroll
        for (int r = 0; r < 4; ++r) {
            float s = run_s[t][r], m = run_m[t][r];
            #pragma unroll
            for (int off = 1; off < 16; off <<= 1) {
                s += __shfl_xor(s, off);
                m = fmaxf(m, __shfl_xor(m, off));
            }
            if (col == 0) {
                int ch = t * 16 + lg * 4 + r;
                red[(wv * 32 + ch) * 2 + 0] = s;
                red[(wv * 32 + ch) * 2 + 1] = m;
            }
        }
    __syncthreads();
    if (tid < 32) {
        float s = red[tid*2] + red[(32+tid)*2] + red[(64+tid)*2] + red[(96+tid)*2];
        float m = fmaxf(fmaxf(red[tid*2+1], red[(32+tid)*2+1]),
                        fmaxf(red[(64+tid)*2+1], red[(96+tid)*2+1]));
        atomicAdd(&sums[b*32 + tid], s);
        unsigned ub  = __float_as_uint(m);
        unsigned key = (ub & 0x80000000u) ? ~ub : (ub | 0x80000000u);
        atomicMax(&maxu[b*32 + tid], key);
    }
}

// ---------------------------------------------------------------------------
// Kernel B: finish ta mean/max, run pgm MLP on both, alpha = sum.
// ---------------------------------------------------------------------------
__global__ __launch_bounds__(256) void kB(
    const float* __restrict__ sums, const unsigned* __restrict__ maxu,
    const float* __restrict__ aw1, const float* __restrict__ ab1,
    const float* __restrict__ aw2, const float* __restrict__ ab2,
    const float* __restrict__ aw3, const float* __restrict__ ab3,
    float* __restrict__ out)
{
    __shared__ float xa[8][32], xm[8][32], h1a[8][32], h1m[8][32];
    const int tid = threadIdx.x;
    const int b = tid >> 5, i = tid & 31;

    xa[b][i] = sums[b*32 + i] * (1.f/65536.f);
    unsigned u = maxu[b*32 + i];
    unsigned bits = (u & 0x80000000u) ? (u ^ 0x80000000u) : ~u;
    xm[b][i] = __uint_as_float(bits);
    __syncthreads();

    float sa = ab1[i], sm = ab1[i];
    #pragma unroll
    for (int j = 0; j < 32; ++j) {
        float w = aw1[i*32 + j];
        sa += w * xa[b][j]; sm += w * xm[b][j];
    }
    __syncthreads();
    h1a[b][i] = leaky(sa); h1m[b][i] = leaky(sm);
    __syncthreads();

    sa = ab2[i]; sm = ab2[i];
    #pragma unroll
    for (int j = 0; j < 32; ++j) {
        float w = aw2[i*32 + j];
        sa += w * h1a[b][j]; sm += w * h1m[b][j];
    }
    float h2a = leaky(sa), h2m = leaky(sm);

    float pa = aw3[i] * h2a, pm = aw3[i] * h2m;
    #pragma unroll
    for (int off = 16; off > 0; off >>= 1) {
        pa += __shfl_xor(pa, off);
        pm += __shfl_xor(pm, off);
    }
    if (i == 0) {
        float za = fmaxf(pa + ab3[0], 0.f) + 1e-6f;
        float zm = fmaxf(pm + ab3[0], 0.f) + 1e-6f;
        out[b] = za + zm;
    }
}

// ---------------------------------------------------------------------------
// Kernel C1: b1 = leaky(conv3x3(xc, bw1, bb1)), 2 -> 16 channels.
// ---------------------------------------------------------------------------
__global__ __launch_bounds__(256) void kC1(
    const float* __restrict__ xc, const float* __restrict__ bw1,
    const float* __restrict__ bb1, float* __restrict__ b1out)
{
    const int idx = blockIdx.x * 256 + threadIdx.x;
    const int b = idx >> 16, rem = idx & 65535;
    const int h = rem >> 8, w = rem & 255;
    float acc[16];
    #pragma unroll
    for (int o = 0; o < 16; ++o) acc[o] = bb1[o];
    #pragma unroll
    for (int ic = 0; ic < 2; ++ic) {
        const float* src = xc + (((size_t)b*2 + ic) << 16);
        #pragma unroll
        for (int dy = 0; dy < 3; ++dy) {
            int hh = h + dy - 1;
            #pragma unroll
            for (int dx = 0; dx < 3; ++dx) {
                int ww = w + dx - 1;
                float v = ((unsigned)hh < 256u && (unsigned)ww < 256u)
                          ? src[(hh << 8) + ww] : 0.f;
                int k = dy*3 + dx;
                #pragma unroll
                for (int o = 0; o < 16; ++o)
                    acc[o] += bw1[(o*2 + ic)*9 + k] * v;
            }
        }
    }
    #pragma unroll
    for (int o = 0; o < 16; ++o)
        b1out[(((size_t)b*16 + o) << 16) + rem] = leaky(acc[o]);
}

// ---------------------------------------------------------------------------
// Kernel C2: b2 = leaky(conv3x3(b1, bw2, bb2)), 16 -> 16 channels.
// ---------------------------------------------------------------------------
__global__ __launch_bounds__(256) void kC2(
    const float* __restrict__ b1in, const float* __restrict__ bw2,
    const float* __restrict__ bb2, float* __restrict__ b2out)
{
    const int idx = blockIdx.x * 256 + threadIdx.x;
    const int b = idx >> 16, rem = idx & 65535;
    const int h = rem >> 8, w = rem & 255;
    float acc[16];
    #pragma unroll
    for (int o = 0; o < 16; ++o) acc[o] = bb2[o];
    #pragma unroll 1
    for (int ic = 0; ic < 16; ++ic) {
        const float* src = b1in + (((size_t)b*16 + ic) << 16);
        #pragma unroll
        for (int dy = 0; dy < 3; ++dy) {
            int hh = h + dy - 1;
            #pragma unroll
            for (int dx = 0; dx < 3; ++dx) {
                int ww = w + dx - 1;
                float v = ((unsigned)hh < 256u && (unsigned)ww < 256u)
                          ? src[(hh << 8) + ww] : 0.f;
                int k = dy*3 + dx;
                #pragma unroll
                for (int o = 0; o < 16; ++o)
                    acc[o] += bw2[(o*16 + ic)*9 + k] * v;
            }
        }
    }
    #pragma unroll
    for (int o = 0; o < 16; ++o)
        b2out[(((size_t)b*16 + o) << 16) + rem] = leaky(acc[o]);
}

// ---------------------------------------------------------------------------
// Kernel C3: beta = sigmoid(conv3x3(b2, bw3, bb3)), 16 -> 1 channel.
// ---------------------------------------------------------------------------
__global__ __launch_bounds__(256) void kC3(
    const float* __restrict__ b2in, const float* __restrict__ bw3,
    const float* __restrict__ bb3, float* __restrict__ betaout)
{
    const int idx = blockIdx.x * 256 + threadIdx.x;
    const int b = idx >> 16, rem = idx & 65535;
    const int h = rem >> 8, w = rem & 255;
    float acc = bb3[0];
    #pragma unroll 1
    for (int ic = 0; ic < 16; ++ic) {
        const float* src = b2in + (((size_t)b*16 + ic) << 16);
        #pragma unroll
        for (int dy = 0; dy < 3; ++dy) {
            int hh = h + dy - 1;
            #pragma unroll
            for (int dx = 0; dx < 3; ++dx) {
                int ww = w + dx - 1;
                float v = ((unsigned)hh < 256u && (unsigned)ww < 256u)
                          ? src[(hh << 8) + ww] : 0.f;
                acc += bw3[ic*9 + dy*3 + dx] * v;
            }
        }
    }
    betaout[idx] = 1.f / (1.f + expf(-acc));
}

// ---------------------------------------------------------------------------
extern "C" void kernel_launch(void* const* d_in, const int* in_sizes, int n_in,
                              void* d_out, int out_size, void* d_ws, size_t ws_size,
                              hipStream_t stream) {
    const float* y    = (const float*)d_in[0];
    const float* mask = (const float*)d_in[1];
    const float* fw1  = (const float*)d_in[2];
    const float* fb1  = (const float*)d_in[3];
    const float* fw2  = (const float*)d_in[4];
    const float* fb2  = (const float*)d_in[5];
    const float* aw1  = (const float*)d_in[6];
    const float* ab1  = (const float*)d_in[7];
    const float* aw2  = (const float*)d_in[8];
    const float* ab2  = (const float*)d_in[9];
    const float* aw3  = (const float*)d_in[10];
    const float* ab3  = (const float*)d_in[11];
    const float* bw1  = (const float*)d_in[12];
    const float* bb1  = (const float*)d_in[13];
    const float* bw2  = (const float*)d_in[14];
    const float* bb2  = (const float*)d_in[15];
    const float* bw3  = (const float*)d_in[16];
    const float* bb3  = (const float*)d_in[17];
    float* out = (float*)d_out;

    char* ws = (char*)d_ws;
    float*    sums = (float*)ws;                               // 1 KB
    unsigned* maxu = (unsigned*)(ws + 1024);                   // 1 KB
    float*    xc   = (float*)(ws + 4096);                      // 4 MB
    float*    b1   = (float*)(ws + 4096 + 4194304);            // 33.5 MB
    float*    b2   = (float*)(ws + 4096 + 4194304 + 33554432); // 33.5 MB

    kInit<<<1, 256, 0, stream>>>(sums, maxu);
    kA<<<dim3(16, 16, 8), 256, 0, stream>>>(y, mask, fw1, fb1, fw2, fb2,
                                            xc, sums, maxu);
    kB<<<1, 256, 0, stream>>>(sums, maxu, aw1, ab1, aw2, ab2, aw3, ab3, out);
    kC1<<<2048, 256, 0, stream>>>(xc, bw1, bb1, b1);
    kC2<<<2048, 256, 0, stream>>>(b1, bw2, bb2, b2);
    kC3<<<2048, 256, 0, stream>>>(b2, bw3, bb3, out + 8);
}